// Round 6
// baseline (205.261 us; speedup 1.0000x reference)
//
#include <hip/hip_runtime.h>
#include <math.h>

#define SEQ  2048
#define NROW 16384   // 8 * 2048
#define HEAD 64
#define EMB  1024

typedef __attribute__((ext_vector_type(8))) short short8;   // 8 bf16 = 4 VGPRs
typedef __attribute__((ext_vector_type(4))) float f32x4;    // MFMA 16x16 acc

// fp32 -> bf16 bits, round-to-nearest-even (inputs finite)
static __device__ __forceinline__ unsigned short f2bf(float f) {
    unsigned u = __builtin_bit_cast(unsigned, f);
    u += 0x7fffu + ((u >> 16) & 1u);
    return (unsigned short)(u >> 16);
}
static __device__ __forceinline__ float bf2f(unsigned short u) {
    unsigned v = (unsigned)u << 16;
    return __builtin_bit_cast(float, v);
}
static __device__ __forceinline__ short8 cvt8(float4 a, float4 b) {
    short8 r;
    r[0] = f2bf(a.x); r[1] = f2bf(a.y); r[2] = f2bf(a.z); r[3] = f2bf(a.w);
    r[4] = f2bf(b.x); r[5] = f2bf(b.y); r[6] = f2bf(b.z); r[7] = f2bf(b.w);
    return r;
}

// ---------------------------------------------------------------------------
// One-off: Wq|Wk|Wv fp32 [64][1024] -> contiguous bf16 [192][1024].
// ---------------------------------------------------------------------------
__global__ __launch_bounds__(256) void wcvt_kernel(
    const float* __restrict__ Wq, const float* __restrict__ Wk,
    const float* __restrict__ Wv, unsigned short* __restrict__ Wb)
{
    const int idx = (blockIdx.x * 256 + threadIdx.x) * 4;  // < 196608
    const int h = idx >> 10;
    const float* src;
    if (h < 64)       src = Wq + idx;
    else if (h < 128) src = Wk + (idx - 65536);
    else              src = Wv + (idx - 131072);
    float4 f = *(const float4*)src;
    ushort4 o;
    o.x = f2bf(f.x); o.y = f2bf(f.y); o.z = f2bf(f.z); o.w = f2bf(f.w);
    *(ushort4*)(Wb + idx) = o;
}

// ---------------------------------------------------------------------------
// QKV projection, bf16 MFMA, x-stationary / barrier-minimal:
// Block = 256 thr = 4 waves, 32 rows. Stage x tile (32 x 1024, fp32->bf16)
// into LDS ONCE (one barrier), then stream B frags straight from L2-resident
// Wb with a barrier-free k-loop (32 steps x 6 tiles; ~190 independent loads
// per wave -> deep pipelining). Wave: mh = w&1 (16 rows), nh = w>>1 (96
// heads = 6 n-tiles). Grid 512 -> 2 blocks/CU (66 KB LDS each).
// q is pre-scaled by 0.125 (exact pow2) so attn skips the softmax scale.
// Outputs bf16: qN[row][h], kN[row][h], vT[h][row] (MFMA A/B frag layouts).
// ---------------------------------------------------------------------------
__global__ __launch_bounds__(256, 2) void qkv_mfma_kernel(
    const float* __restrict__ x, const unsigned short* __restrict__ Wb,
    unsigned short* __restrict__ qN, unsigned short* __restrict__ kN,
    unsigned short* __restrict__ vT)
{
    __shared__ unsigned short xs[32][1032];   // 66 KB; stride 1032 -> min-phase frag reads

    const int tid  = threadIdx.x;
    const int w    = tid >> 6;
    const int lane = tid & 63;
    const int col  = lane & 15;
    const int quad = lane >> 4;
    const int mh   = w & 1;
    const int nh   = w >> 1;
    const int row0 = blockIdx.x * 32;

    // stage x tile: 32 rows x 1024 fp32, coalesced, cvt to bf16 in-register
#pragma unroll
    for (int it = 0; it < 16; ++it) {
        int c  = it * 256 + tid;      // 8-float chunk id (4096 total)
        int rw = c >> 7;              // 128 chunks per row
        int ch = c & 127;
        const float* p = x + (size_t)(row0 + rw) * EMB + ch * 8;
        float4 f0 = *(const float4*)p;
        float4 f1 = *(const float4*)(p + 4);
        *(short8*)&xs[rw][ch * 8] = cvt8(f0, f1);
    }
    __syncthreads();   // the only barrier

    // B frag pointer: frag(t, ks) = bb[t*2048 + ks*4]
    const short8* bb = (const short8*)Wb + (size_t)(nh * 96 + col) * 128 + quad;

    f32x4 acc[6];
#pragma unroll
    for (int t = 0; t < 6; ++t) acc[t] = (f32x4){0.f, 0.f, 0.f, 0.f};

#pragma unroll 4
    for (int ks = 0; ks < 32; ++ks) {
        short8 af = *(const short8*)&xs[mh * 16 + col][ks * 32 + quad * 8];
#pragma unroll
        for (int t = 0; t < 6; ++t) {
            short8 bf = bb[t * 2048 + ks * 4];
            acc[t] = __builtin_amdgcn_mfma_f32_16x16x32_bf16(af, bf, acc[t], 0, 0, 0);
        }
    }

    // epilogue: heads hb = nh*96 + 16t; rows ro = row0 + mh*16 + quad*4
    const int ro = row0 + mh * 16 + quad * 4;
#pragma unroll
    for (int t = 0; t < 6; ++t) {
        const int hb = nh * 96 + 16 * t;   // wave-uniform
        const int h  = hb + col;
        if (hb < 64) {
#pragma unroll
            for (int r = 0; r < 4; ++r)    // pre-scale q by 1/sqrt(64) (exact)
                qN[(size_t)(ro + r) * HEAD + h] = f2bf(acc[t][r] * 0.125f);
        } else if (hb < 128) {
#pragma unroll
            for (int r = 0; r < 4; ++r)
                kN[(size_t)(ro + r) * HEAD + (h - 64)] = f2bf(acc[t][r]);
        } else {
            ushort4 uv;
            uv.x = f2bf(acc[t][0]); uv.y = f2bf(acc[t][1]);
            uv.z = f2bf(acc[t][2]); uv.w = f2bf(acc[t][3]);
            *(ushort4*)(vT + (size_t)(h - 128) * NROW + ro) = uv;
        }
    }
}

// ---------------------------------------------------------------------------
// Flash attention, bf16 MFMA, BARRIER-FREE. Block = 256 thr = 4 waves, each
// wave independently owns 16 q-rows of a 64-row strip (no cross-wave state).
// K/V fragments loaded directly from L2-resident kN/vT (verified round-4
// index pattern); P transposed through a private per-wave LDS buffer
// (same-wave ds_write->ds_read, no barrier). Split-K P=2 via blockIdx.z ->
// op/ml partials merged by merge_kernel. Grid (32, 8, 2), qt descending.
// q arrives pre-scaled by 0.125.
// ---------------------------------------------------------------------------
__global__ __launch_bounds__(256, 2) void attn_kernel(
    const unsigned short* __restrict__ qN,
    const unsigned short* __restrict__ kN,
    const unsigned short* __restrict__ vT,
    unsigned short* __restrict__ op,      // [2][NROW][HEAD] bf16 partial O
    float2* __restrict__ ml)              // [2][NROW] {m, l}
{
    __shared__ float Pl[4][16][68];       // per-wave P transpose buffer

    const int qt   = 31 - (int)blockIdx.x;     // descending: big work first
    const int b    = blockIdx.y;
    const int p    = blockIdx.z;
    const int tid  = threadIdx.x;
    const int wv   = tid >> 6;
    const int lane = tid & 63;
    const int col  = lane & 15;
    const int quad = lane >> 4;

    const int q0   = qt * 64 + wv * 16;        // wave's q rows (batch-local)
    const int q0g  = b * SEQ + q0;
    const int Cb   = qt + 1;                   // kt tiles for this strip
    const int half = (Cb + 1) >> 1;
    const int kt0  = p ? half : 0;
    const int kt1  = p ? Cb : half;

    // Q A-fragments (A[m=col][k=quad*8+j+32s]), once per wave
    const short8* qp8 = (const short8*)qN + (size_t)(q0g + col) * 8;
    short8 aq0 = qp8[quad];
    short8 aq1 = qp8[quad + 4];

    f32x4 o[4];
#pragma unroll
    for (int t = 0; t < 4; ++t) o[t] = (f32x4){0.f, 0.f, 0.f, 0.f};
    float m_i[4], l_i[4];
#pragma unroll
    for (int r = 0; r < 4; ++r) { m_i[r] = -INFINITY; l_i[r] = 0.0f; }

    for (int kt = kt0; kt < kt1; ++kt) {
        const int s0  = kt * 64;
        const int s0g = b * SEQ + s0;
        const bool diag = (kt == Cb - 1);

        // K B-frags: B[n = key-row 16t+col][k = head] straight from L2
        short8 kf[4][2];
#pragma unroll
        for (int t = 0; t < 4; ++t) {
            const short8* kp8 = (const short8*)kN + (size_t)(s0g + 16 * t + col) * 8;
            kf[t][0] = kp8[quad];
            kf[t][1] = kp8[quad + 4];
        }
        // V B-frags: B[n = head 16tn+col][k = key-row] from vT[h][NROW]
        short8 vf[4][2];
#pragma unroll
        for (int tn = 0; tn < 4; ++tn) {
            const short8* vp8 = (const short8*)vT + (size_t)(16 * tn + col) * 2048 + (s0g >> 3);
            vf[tn][0] = vp8[quad];
            vf[tn][1] = vp8[quad + 4];
        }

        // S = Q K^T (q pre-scaled)
        f32x4 sv[4];
#pragma unroll
        for (int t = 0; t < 4; ++t) {
            sv[t] = (f32x4){0.f, 0.f, 0.f, 0.f};
            sv[t] = __builtin_amdgcn_mfma_f32_16x16x32_bf16(aq0, kf[t][0], sv[t], 0, 0, 0);
            sv[t] = __builtin_amdgcn_mfma_f32_16x16x32_bf16(aq1, kf[t][1], sv[t], 0, 0, 0);
        }

        // causal mask + online softmax (rows = quad*4+r, cols in lanes)
        float pv[4][4];
#pragma unroll
        for (int r = 0; r < 4; ++r) {
            const int grow = q0 + quad * 4 + r;
            float rm = -INFINITY;
#pragma unroll
            for (int t = 0; t < 4; ++t) {
                float val = sv[t][r];
                if (diag && (s0 + 16 * t + col > grow)) val = -INFINITY;
                pv[t][r] = val;
                rm = fmaxf(rm, val);
            }
            rm = fmaxf(rm, __shfl_xor(rm, 1, 16));
            rm = fmaxf(rm, __shfl_xor(rm, 2, 16));
            rm = fmaxf(rm, __shfl_xor(rm, 4, 16));
            rm = fmaxf(rm, __shfl_xor(rm, 8, 16));
            const float mnew  = fmaxf(m_i[r], rm);
            const float alpha = __expf(m_i[r] - mnew);
            m_i[r] = mnew;
            float ls = 0.0f;
#pragma unroll
            for (int t = 0; t < 4; ++t) {
                float e = __expf(pv[t][r] - mnew);
                pv[t][r] = e;
                ls += e;
            }
            ls += __shfl_xor(ls, 1, 16);
            ls += __shfl_xor(ls, 2, 16);
            ls += __shfl_xor(ls, 4, 16);
            ls += __shfl_xor(ls, 8, 16);
            l_i[r] = l_i[r] * alpha + ls;
#pragma unroll
            for (int tn = 0; tn < 4; ++tn) o[tn][r] *= alpha;
        }

        // P: C/D layout -> private LDS slice -> A-operand layout (bf16)
#pragma unroll
        for (int t = 0; t < 4; ++t)
#pragma unroll
            for (int r = 0; r < 4; ++r)
                Pl[wv][quad * 4 + r][16 * t + col] = pv[t][r];
        short8 pf[2];
#pragma unroll
        for (int st = 0; st < 2; ++st) {
            float4 pa = *(const float4*)&Pl[wv][col][quad * 8 + 32 * st];
            float4 pb = *(const float4*)&Pl[wv][col][quad * 8 + 32 * st + 4];
            pf[st] = cvt8(pa, pb);
        }

        // O += P V
#pragma unroll
        for (int tn = 0; tn < 4; ++tn) {
            o[tn] = __builtin_amdgcn_mfma_f32_16x16x32_bf16(pf[0], vf[tn][0], o[tn], 0, 0, 0);
            o[tn] = __builtin_amdgcn_mfma_f32_16x16x32_bf16(pf[1], vf[tn][1], o[tn], 0, 0, 0);
        }
    }

    // store this wave's partial (bf16 o, fp32 m/l)
#pragma unroll
    for (int tn = 0; tn < 4; ++tn)
#pragma unroll
        for (int r = 0; r < 4; ++r)
            op[(size_t)(p * NROW + q0g + quad * 4 + r) * HEAD + 16 * tn + col] =
                f2bf(o[tn][r]);
    if (col == 0) {
#pragma unroll
        for (int r = 0; r < 4; ++r)
            ml[p * NROW + q0g + quad * 4 + r] = make_float2(m_i[r], l_i[r]);
    }
}

// ---------------------------------------------------------------------------
// Combine the two split-K partials.
// ---------------------------------------------------------------------------
__global__ __launch_bounds__(256) void merge_kernel(
    const unsigned short* __restrict__ op, const float2* __restrict__ ml,
    float* __restrict__ out)
{
    const int idx = blockIdx.x * 256 + threadIdx.x;   // 262144 total
    const int row = idx >> 4;
    const int hc  = (idx & 15) * 4;

    float2 e0 = ml[row];
    float2 e1 = ml[NROW + row];
    float m  = fmaxf(e0.x, e1.x);
    float w0 = (e0.x > -INFINITY) ? __expf(e0.x - m) : 0.0f;
    float w1 = (e1.x > -INFINITY) ? __expf(e1.x - m) : 0.0f;
    float inv = 1.0f / (e0.y * w0 + e1.y * w1);

    ushort4 u0 = *(const ushort4*)(op + (size_t)row * HEAD + hc);
    ushort4 u1 = *(const ushort4*)(op + (size_t)(NROW + row) * HEAD + hc);
    float4 r;
    r.x = (bf2f(u0.x) * w0 + bf2f(u1.x) * w1) * inv;
    r.y = (bf2f(u0.y) * w0 + bf2f(u1.y) * w1) * inv;
    r.z = (bf2f(u0.z) * w0 + bf2f(u1.z) * w1) * inv;
    r.w = (bf2f(u0.w) * w0 + bf2f(u1.w) * w1) * inv;
    *(float4*)(out + (size_t)row * HEAD + hc) = r;
}

extern "C" void kernel_launch(void* const* d_in, const int* in_sizes, int n_in,
                              void* d_out, int out_size, void* d_ws, size_t ws_size,
                              hipStream_t stream)
{
    const float* x  = (const float*)d_in[0];
    const float* Wq = (const float*)d_in[1];
    const float* Wk = (const float*)d_in[2];
    const float* Wv = (const float*)d_in[3];

    char* w = (char*)d_ws;
    unsigned short* qN = (unsigned short*)w;                       // 2 MB
    unsigned short* kN = (unsigned short*)(w + (2u << 20));        // 2 MB
    unsigned short* vT = (unsigned short*)(w + (4u << 20));        // 2 MB
    unsigned short* Wb = (unsigned short*)(w + (6u << 20));        // 384 KB
    unsigned short* op = (unsigned short*)(w + (6u << 20) + 393216);   // 4 MB
    float2*         ml = (float2*)(w + (10u << 20) + 393216);      // 256 KB
    float* out = (float*)d_out;

    wcvt_kernel<<<192, 256, 0, stream>>>(Wq, Wk, Wv, Wb);
    qkv_mfma_kernel<<<512, 256, 0, stream>>>(x, Wb, qN, kN, vT);
    attn_kernel<<<dim3(32, 8, 2), 256, 0, stream>>>(qN, kN, vT, op, ml);
    merge_kernel<<<1024, 256, 0, stream>>>(op, ml, out);
}

// Round 7
// 150.650 us; speedup vs baseline: 1.3625x; 1.3625x over previous
//
#include <hip/hip_runtime.h>
#include <math.h>

#define SEQ  2048
#define NROW 16384   // 8 * 2048
#define HEAD 64
#define EMB  1024

typedef __attribute__((ext_vector_type(8))) short short8;   // 8 bf16 = 4 VGPRs
typedef __attribute__((ext_vector_type(4))) float f32x4;    // MFMA 16x16 acc

// fp32 -> bf16 bits, round-to-nearest-even (inputs finite)
static __device__ __forceinline__ unsigned short f2bf(float f) {
    unsigned u = __builtin_bit_cast(unsigned, f);
    u += 0x7fffu + ((u >> 16) & 1u);
    return (unsigned short)(u >> 16);
}
static __device__ __forceinline__ float bf2f(unsigned short u) {
    unsigned v = (unsigned)u << 16;
    return __builtin_bit_cast(float, v);
}
static __device__ __forceinline__ short8 cvt8(float4 a, float4 b) {
    short8 r;
    r[0] = f2bf(a.x); r[1] = f2bf(a.y); r[2] = f2bf(a.z); r[3] = f2bf(a.w);
    r[4] = f2bf(b.x); r[5] = f2bf(b.y); r[6] = f2bf(b.z); r[7] = f2bf(b.w);
    return r;
}

// ---------------------------------------------------------------------------
// One-off: Wq|Wk|Wv fp32 [64][1024] -> contiguous bf16 [192][1024].
// ---------------------------------------------------------------------------
__global__ __launch_bounds__(256) void wcvt_kernel(
    const float* __restrict__ Wq, const float* __restrict__ Wk,
    const float* __restrict__ Wv, unsigned short* __restrict__ Wb)
{
    const int idx = (blockIdx.x * 256 + threadIdx.x) * 4;  // < 196608
    const int h = idx >> 10;
    const float* src;
    if (h < 64)       src = Wq + idx;
    else if (h < 128) src = Wk + (idx - 65536);
    else              src = Wv + (idx - 131072);
    float4 f = *(const float4*)src;
    ushort4 o;
    o.x = f2bf(f.x); o.y = f2bf(f.y); o.z = f2bf(f.z); o.w = f2bf(f.w);
    *(ushort4*)(Wb + idx) = o;
}

// ---------------------------------------------------------------------------
// QKV projection, bf16 MFMA, LDS double-buffered single-barrier pipeline.
// Block = 256 thr = 4 waves; tile BM=64 x BN=96, BK=64, 16 k-iterations.
// Per iter: (a) global loads for k+1 -> regs, (b) frags from buf[k&1] + MFMA,
// (c) ds_write regs -> buf[(k+1)&1], (d) ONE barrier. Loads coalesced
// (lane-contiguous 256 B / 128 B row segments); frag reads from padded LDS
// (<=2-way bank aliasing). Wave w owns rows [16w,16w+16), all 6 n-tiles.
// Grid (256, 2) = 512 blocks, 2/CU (61 KB LDS).
// q pre-scaled by 0.125 (exact). Outputs bf16: qN[row][h], kN[row][h],
// vT[h][row] (MFMA A/B fragment layouts for attn).
// ---------------------------------------------------------------------------
__global__ __launch_bounds__(256, 2) void qkv_mfma_kernel(
    const float* __restrict__ x, const unsigned short* __restrict__ Wb,
    unsigned short* __restrict__ qN, unsigned short* __restrict__ kN,
    unsigned short* __restrict__ vT)
{
    __shared__ float          As[2][64][68];   // 34.8 KB
    __shared__ unsigned short Bs[2][96][68];   // 26.1 KB

    const int tid  = threadIdx.x;
    const int w    = tid >> 6;
    const int lane = tid & 63;
    const int col  = lane & 15;
    const int quad = lane >> 4;
    const int row0 = blockIdx.x * 64;
    const int ny   = blockIdx.y;            // head half (96 heads)
    const int arow = w * 16 + col;          // this wave's A-frag row in LDS

    // staging index decomposition (flat = i*256 + tid)
    const int ar_r = tid >> 4, ar_c = tid & 15;   // A: +16 rows per i
    const int br_h = tid >> 3, br_c = tid & 7;    // B: +32 rows per i

    const float*          xg = x  + (size_t)(row0 + ar_r) * EMB + ar_c * 4;
    const unsigned short* bg = Wb + (size_t)(ny * 96 + br_h) * EMB + br_c * 8;

    float4 ar[4];
    short8 br[3];
    // prologue: load k-iter 0
#pragma unroll
    for (int i = 0; i < 4; ++i) ar[i] = *(const float4*)(xg + (size_t)(16 * i) * EMB);
#pragma unroll
    for (int i = 0; i < 3; ++i) br[i] = *(const short8*)(bg + (size_t)(32 * i) * EMB);
#pragma unroll
    for (int i = 0; i < 4; ++i) *(float4*)&As[0][ar_r + 16 * i][ar_c * 4] = ar[i];
#pragma unroll
    for (int i = 0; i < 3; ++i) *(short8*)&Bs[0][br_h + 32 * i][br_c * 8] = br[i];
    __syncthreads();

    f32x4 acc[6];
#pragma unroll
    for (int t = 0; t < 6; ++t) acc[t] = (f32x4){0.f, 0.f, 0.f, 0.f};

    for (int kt = 0; kt < 16; ++kt) {
        const int cur = kt & 1;
        // (a) issue global loads for kt+1
        if (kt + 1 < 16) {
            const int k0 = (kt + 1) * 64;
#pragma unroll
            for (int i = 0; i < 4; ++i)
                ar[i] = *(const float4*)(xg + (size_t)(16 * i) * EMB + k0);
#pragma unroll
            for (int i = 0; i < 3; ++i)
                br[i] = *(const short8*)(bg + (size_t)(32 * i) * EMB + k0);
        }
        // (b) compute from buf[cur]
#pragma unroll
        for (int ks = 0; ks < 2; ++ks) {
            float4 a0 = *(const float4*)&As[cur][arow][ks * 32 + quad * 8];
            float4 a1 = *(const float4*)&As[cur][arow][ks * 32 + quad * 8 + 4];
            short8 af = cvt8(a0, a1);
#pragma unroll
            for (int t = 0; t < 6; ++t) {
                short8 bf = *(const short8*)&Bs[cur][t * 16 + col][ks * 32 + quad * 8];
                acc[t] = __builtin_amdgcn_mfma_f32_16x16x32_bf16(af, bf, acc[t], 0, 0, 0);
            }
        }
        // (c) stage kt+1 into the other buffer
        if (kt + 1 < 16) {
#pragma unroll
            for (int i = 0; i < 4; ++i) *(float4*)&As[cur ^ 1][ar_r + 16 * i][ar_c * 4] = ar[i];
#pragma unroll
            for (int i = 0; i < 3; ++i) *(short8*)&Bs[cur ^ 1][br_h + 32 * i][br_c * 8] = br[i];
        }
        // (d) single barrier
        __syncthreads();
    }

    // epilogue: rows ro = row0 + 16w + quad*4; heads hb = ny*96 + 16t
    const int ro = row0 + w * 16 + quad * 4;
#pragma unroll
    for (int t = 0; t < 6; ++t) {
        const int hb = ny * 96 + 16 * t;   // wave-uniform
        const int h  = hb + col;
        if (hb < 64) {
#pragma unroll
            for (int r = 0; r < 4; ++r)    // pre-scale q by 1/sqrt(64) (exact)
                qN[(size_t)(ro + r) * HEAD + h] = f2bf(acc[t][r] * 0.125f);
        } else if (hb < 128) {
#pragma unroll
            for (int r = 0; r < 4; ++r)
                kN[(size_t)(ro + r) * HEAD + (h - 64)] = f2bf(acc[t][r]);
        } else {
            ushort4 uv;
            uv.x = f2bf(acc[t][0]); uv.y = f2bf(acc[t][1]);
            uv.z = f2bf(acc[t][2]); uv.w = f2bf(acc[t][3]);
            *(ushort4*)(vT + (size_t)(h - 128) * NROW + ro) = uv;
        }
    }
}

// ---------------------------------------------------------------------------
// Flash attention, bf16 MFMA, LDS double-buffered single-barrier pipeline.
// Block = 256 thr = 4 waves sharing a 64-row q-strip; wave wv owns rows
// [q64+16wv,+16) (no cross-wave state). K/V tiles (64x64 bf16) staged
// coalesced, double-buffered; per iter one barrier. P transposed through a
// private per-wave LDS slice (same-wave, no barrier). Split-K P=2 via
// blockIdx.z -> op/ml partials + merge_kernel. Grid (32, 8, 2), qt
// descending. q arrives pre-scaled by 0.125.
// ---------------------------------------------------------------------------
__global__ __launch_bounds__(256, 3) void attn_kernel(
    const unsigned short* __restrict__ qN,
    const unsigned short* __restrict__ kN,
    const unsigned short* __restrict__ vT,
    unsigned short* __restrict__ op,      // [2][NROW][HEAD] bf16 partial O
    float2* __restrict__ ml)              // [2][NROW] {m, l}
{
    __shared__ unsigned short Ks[2][64][68];   // 17.4 KB
    __shared__ unsigned short Vs[2][64][68];   // 17.4 KB
    __shared__ float Pl[4][16][68];            // 17.4 KB (per-wave slices)

    const int qt   = 31 - (int)blockIdx.x;     // descending: big work first
    const int b    = blockIdx.y;
    const int p    = blockIdx.z;
    const int tid  = threadIdx.x;
    const int wv   = tid >> 6;
    const int lane = tid & 63;
    const int col  = lane & 15;
    const int quad = lane >> 4;

    const int q0   = qt * 64 + wv * 16;        // wave's q rows (batch-local)
    const int q0g  = b * SEQ + q0;
    const int Cb   = qt + 1;                   // kt tiles (block-uniform)
    const int half = (Cb + 1) >> 1;
    const int kt0  = p ? half : 0;
    const int kt1  = p ? Cb : half;

    // staging decomposition: flat = i*256 + tid, 2 chunks each for K and V
    const int st_r = tid >> 3, st_c = tid & 7;   // +32 rows per i

    const unsigned short* kg = kN + (size_t)(b * SEQ + st_r) * HEAD + st_c * 8;
    const unsigned short* vg = vT + (size_t)st_r * NROW + b * SEQ + st_c * 8;

    // Q A-fragments (A[m=col][k=quad*8+j+32s]), once per wave
    const short8* qp8 = (const short8*)qN + (size_t)(q0g + col) * 8;
    short8 aq0 = qp8[quad];
    short8 aq1 = qp8[quad + 4];

    f32x4 o[4];
#pragma unroll
    for (int t = 0; t < 4; ++t) o[t] = (f32x4){0.f, 0.f, 0.f, 0.f};
    float m_i[4], l_i[4];
#pragma unroll
    for (int r = 0; r < 4; ++r) { m_i[r] = -INFINITY; l_i[r] = 0.0f; }

    short8 kr[2], vr[2];
    // prologue: load tile kt0
#pragma unroll
    for (int i = 0; i < 2; ++i) {
        kr[i] = *(const short8*)(kg + (size_t)(kt0 * 64 + 32 * i) * HEAD);
        vr[i] = *(const short8*)(vg + (size_t)(32 * i) * NROW + kt0 * 64);
    }
#pragma unroll
    for (int i = 0; i < 2; ++i) {
        *(short8*)&Ks[0][st_r + 32 * i][st_c * 8] = kr[i];
        *(short8*)&Vs[0][st_r + 32 * i][st_c * 8] = vr[i];
    }
    __syncthreads();

    for (int kt = kt0; kt < kt1; ++kt) {
        const int cur = (kt - kt0) & 1;
        const int s0  = kt * 64;
        const bool diag = (kt == Cb - 1);

        // (a) issue loads for kt+1
        if (kt + 1 < kt1) {
#pragma unroll
            for (int i = 0; i < 2; ++i) {
                kr[i] = *(const short8*)(kg + (size_t)((kt + 1) * 64 + 32 * i) * HEAD);
                vr[i] = *(const short8*)(vg + (size_t)(32 * i) * NROW + (kt + 1) * 64);
            }
        }

        // (b) compute from buf[cur]
        // S = Q K^T : B[n = key-row 16t+col][k = head]
        f32x4 sv[4];
#pragma unroll
        for (int t = 0; t < 4; ++t) {
            short8 kf0 = *(const short8*)&Ks[cur][16 * t + col][quad * 8];
            short8 kf1 = *(const short8*)&Ks[cur][16 * t + col][32 + quad * 8];
            sv[t] = (f32x4){0.f, 0.f, 0.f, 0.f};
            sv[t] = __builtin_amdgcn_mfma_f32_16x16x32_bf16(aq0, kf0, sv[t], 0, 0, 0);
            sv[t] = __builtin_amdgcn_mfma_f32_16x16x32_bf16(aq1, kf1, sv[t], 0, 0, 0);
        }

        // causal mask + online softmax (rows = quad*4+r, cols in lanes)
        float pv[4][4];
#pragma unroll
        for (int r = 0; r < 4; ++r) {
            const int grow = q0 + quad * 4 + r;
            float rm = -INFINITY;
#pragma unroll
            for (int t = 0; t < 4; ++t) {
                float val = sv[t][r];
                if (diag && (s0 + 16 * t + col > grow)) val = -INFINITY;
                pv[t][r] = val;
                rm = fmaxf(rm, val);
            }
            rm = fmaxf(rm, __shfl_xor(rm, 1, 16));
            rm = fmaxf(rm, __shfl_xor(rm, 2, 16));
            rm = fmaxf(rm, __shfl_xor(rm, 4, 16));
            rm = fmaxf(rm, __shfl_xor(rm, 8, 16));
            const float mnew  = fmaxf(m_i[r], rm);
            const float alpha = __expf(m_i[r] - mnew);
            m_i[r] = mnew;
            float ls = 0.0f;
#pragma unroll
            for (int t = 0; t < 4; ++t) {
                float e = __expf(pv[t][r] - mnew);
                pv[t][r] = e;
                ls += e;
            }
            ls += __shfl_xor(ls, 1, 16);
            ls += __shfl_xor(ls, 2, 16);
            ls += __shfl_xor(ls, 4, 16);
            ls += __shfl_xor(ls, 8, 16);
            l_i[r] = l_i[r] * alpha + ls;
#pragma unroll
            for (int tn = 0; tn < 4; ++tn) o[tn][r] *= alpha;
        }

        // P: C/D layout -> private LDS slice -> A-operand layout (bf16)
#pragma unroll
        for (int t = 0; t < 4; ++t)
#pragma unroll
            for (int r = 0; r < 4; ++r)
                Pl[wv][quad * 4 + r][16 * t + col] = pv[t][r];
        short8 pf[2];
#pragma unroll
        for (int st = 0; st < 2; ++st) {
            float4 pa = *(const float4*)&Pl[wv][col][quad * 8 + 32 * st];
            float4 pb = *(const float4*)&Pl[wv][col][quad * 8 + 32 * st + 4];
            pf[st] = cvt8(pa, pb);
        }

        // O += P V : B[n = head 16tn+col][k = key-row]
#pragma unroll
        for (int tn = 0; tn < 4; ++tn) {
            short8 vf0 = *(const short8*)&Vs[cur][16 * tn + col][quad * 8];
            short8 vf1 = *(const short8*)&Vs[cur][16 * tn + col][32 + quad * 8];
            o[tn] = __builtin_amdgcn_mfma_f32_16x16x32_bf16(pf[0], vf0, o[tn], 0, 0, 0);
            o[tn] = __builtin_amdgcn_mfma_f32_16x16x32_bf16(pf[1], vf1, o[tn], 0, 0, 0);
        }

        // (c) stage kt+1 into the other buffer
        if (kt + 1 < kt1) {
#pragma unroll
            for (int i = 0; i < 2; ++i) {
                *(short8*)&Ks[cur ^ 1][st_r + 32 * i][st_c * 8] = kr[i];
                *(short8*)&Vs[cur ^ 1][st_r + 32 * i][st_c * 8] = vr[i];
            }
        }
        // (d) single barrier
        __syncthreads();
    }

    // store this wave's partial (bf16 o, fp32 m/l)
#pragma unroll
    for (int tn = 0; tn < 4; ++tn)
#pragma unroll
        for (int r = 0; r < 4; ++r)
            op[(size_t)(p * NROW + q0g + quad * 4 + r) * HEAD + 16 * tn + col] =
                f2bf(o[tn][r]);
    if (col == 0) {
#pragma unroll
        for (int r = 0; r < 4; ++r)
            ml[p * NROW + q0g + quad * 4 + r] = make_float2(m_i[r], l_i[r]);
    }
}

// ---------------------------------------------------------------------------
// Combine the two split-K partials.
// ---------------------------------------------------------------------------
__global__ __launch_bounds__(256) void merge_kernel(
    const unsigned short* __restrict__ op, const float2* __restrict__ ml,
    float* __restrict__ out)
{
    const int idx = blockIdx.x * 256 + threadIdx.x;   // 262144 total
    const int row = idx >> 4;
    const int hc  = (idx & 15) * 4;

    float2 e0 = ml[row];
    float2 e1 = ml[NROW + row];
    float m  = fmaxf(e0.x, e1.x);
    float w0 = (e0.x > -INFINITY) ? __expf(e0.x - m) : 0.0f;
    float w1 = (e1.x > -INFINITY) ? __expf(e1.x - m) : 0.0f;
    float inv = 1.0f / (e0.y * w0 + e1.y * w1);

    ushort4 u0 = *(const ushort4*)(op + (size_t)row * HEAD + hc);
    ushort4 u1 = *(const ushort4*)(op + (size_t)(NROW + row) * HEAD + hc);
    float4 r;
    r.x = (bf2f(u0.x) * w0 + bf2f(u1.x) * w1) * inv;
    r.y = (bf2f(u0.y) * w0 + bf2f(u1.y) * w1) * inv;
    r.z = (bf2f(u0.z) * w0 + bf2f(u1.z) * w1) * inv;
    r.w = (bf2f(u0.w) * w0 + bf2f(u1.w) * w1) * inv;
    *(float4*)(out + (size_t)row * HEAD + hc) = r;
}

extern "C" void kernel_launch(void* const* d_in, const int* in_sizes, int n_in,
                              void* d_out, int out_size, void* d_ws, size_t ws_size,
                              hipStream_t stream)
{
    const float* x  = (const float*)d_in[0];
    const float* Wq = (const float*)d_in[1];
    const float* Wk = (const float*)d_in[2];
    const float* Wv = (const float*)d_in[3];

    char* w = (char*)d_ws;
    unsigned short* qN = (unsigned short*)w;                       // 2 MB
    unsigned short* kN = (unsigned short*)(w + (2u << 20));        // 2 MB
    unsigned short* vT = (unsigned short*)(w + (4u << 20));        // 2 MB
    unsigned short* Wb = (unsigned short*)(w + (6u << 20));        // 384 KB
    unsigned short* op = (unsigned short*)(w + (6u << 20) + 393216);   // 4 MB
    float2*         ml = (float2*)(w + (10u << 20) + 393216);      // 256 KB
    float* out = (float*)d_out;

    wcvt_kernel<<<192, 256, 0, stream>>>(Wq, Wk, Wv, Wb);
    qkv_mfma_kernel<<<dim3(256, 2), 256, 0, stream>>>(x, Wb, qN, kN, vT);
    attn_kernel<<<dim3(32, 8, 2), 256, 0, stream>>>(qN, kN, vT, op, ml);
    merge_kernel<<<1024, 256, 0, stream>>>(op, ml, out);
}